// Round 8
// baseline (170.052 us; speedup 1.0000x reference)
//
#include <hip/hip_runtime.h>

#define IMG_H 512
#define IMG_W 512
#define BATCH 32
#define TW 256              // block column span (1 col/thread)
#define TH 16               // output rows per block
#define NROWS (TH + 6)      // 22 input rows
#define NBLK (2 * 32 * 32)  // 2048 blocks

// No LDS staging, no barriers in the row loop, no cross-lane traffic:
// each thread loads its own 7-tap window straight from global (L1-hit for
// the 6/7 overlap with neighbor lanes). All horizontal edge handling is
// folded into loop-invariant clamped indices + masked weights, so SAME
// zero-padding is exact while every load address stays valid.
__global__ __launch_bounds__(256) void ssim_main(
    const float* __restrict__ X, const float* __restrict__ Y,
    const float* __restrict__ K, float* __restrict__ partials) {
  __shared__ float wsum[4];

  const int t = threadIdx.x;
  const int x0 = blockIdx.x * TW;
  const int y0 = blockIdx.y * TH;
  const size_t img = (size_t)IMG_H * IMG_W;
  const float* Xb = X + blockIdx.z * img;
  const float* Yb = Y + blockIdx.z * img;

  // Exact separable 1D weights from center row of the provided 7x7 kernel:
  // k[3][j] = w3*w_j, sum_j w_j = 1  =>  w_j = k[3][j] / sum_j k[3][j].
  float w[7];
  {
    float rs = 0.f;
#pragma unroll
    for (int j = 0; j < 7; ++j) { w[j] = K[3 * 7 + j]; rs += w[j]; }
    const float inv = 1.f / rs;
#pragma unroll
    for (int j = 0; j < 7; ++j) w[j] *= inv;
  }

  // Loop-invariant per-lane tap addressing (this thread's output column).
  const int col = x0 + t;
  int idx[7];    // clamped source columns (always valid addresses)
  float wk[7];   // w[k] masked to 0 for out-of-range taps (exact zero-pad)
#pragma unroll
  for (int k = 0; k < 7; ++k) {
    const int c = col - 3 + k;
    idx[k] = min(max(c, 0), IMG_W - 1);
    wk[k] = ((unsigned)c < (unsigned)IMG_W) ? w[k] : 0.f;
  }

  // mod-7 ring of 5-channel vertical accumulators; fully unrolled row loop
  // keeps every index compile-time.
  float acc[7][5];
#pragma unroll
  for (int s = 0; s < 7; ++s)
#pragma unroll
    for (int c = 0; c < 5; ++c) acc[s][c] = 0.f;
  float tsum = 0.f;

  // Explicit 2-deep register pipeline: 14 values per row, double-buffered.
  float xv[2][7], yv[2][7];
  auto load_row = [&](int r, int b) {
    const int gy = y0 - 3 + r;
    const int gyc = min(max(gy, 0), IMG_H - 1);  // clamped: always valid
    const float* xrow = Xb + (size_t)gyc * IMG_W;
    const float* yrow = Yb + (size_t)gyc * IMG_W;
#pragma unroll
    for (int k = 0; k < 7; ++k) {
      xv[b][k] = xrow[idx[k]];
      yv[b][k] = yrow[idx[k]];
    }
  };

  load_row(0, 0);

#pragma unroll
  for (int r = 0; r < NROWS; ++r) {   // fully unrolled, r compile-time
    const int b = r & 1;
    if (r + 1 < NROWS) load_row(r + 1, b ^ 1);  // prefetch next row

    // horizontal 7-tap, 5 channels (masked weights handle x-edges)
    float hx = 0.f, hy = 0.f, hxx = 0.f, hyy = 0.f, hxy = 0.f;
#pragma unroll
    for (int k = 0; k < 7; ++k) {
      const float xvk = xv[b][k];
      const float yvk = yv[b][k];
      const float wx = wk[k] * xvk;
      const float wy = wk[k] * yvk;
      hx  = fmaf(wk[k], xvk, hx);
      hy  = fmaf(wk[k], yvk, hy);
      hxx = fmaf(wx, xvk, hxx);
      hyy = fmaf(wy, yvk, hyy);
      hxy = fmaf(wx, yvk, hxy);
    }

    // y-edge SAME padding: zero this row's contribution if OOB (branchless)
    const int gy = y0 - 3 + r;
    const float rm = ((unsigned)gy < (unsigned)IMG_H) ? 1.f : 0.f;
    hx *= rm; hy *= rm; hxx *= rm; hyy *= rm; hxy *= rm;

    // vertical scatter into the ring; guards fold at compile time
#pragma unroll
    for (int tt = 0; tt < 7; ++tt) {
      const int o = r - tt;
      if (o >= 0 && o < TH) {
        const int slot = o % 7;
        const float wt = w[tt];
        acc[slot][0] = fmaf(wt, hx,  acc[slot][0]);
        acc[slot][1] = fmaf(wt, hy,  acc[slot][1]);
        acc[slot][2] = fmaf(wt, hxx, acc[slot][2]);
        acc[slot][3] = fmaf(wt, hyy, acc[slot][3]);
        acc[slot][4] = fmaf(wt, hxy, acc[slot][4]);
      }
    }

    // output row r-6 complete
    if (r >= 6) {
      const int slot = (r - 6) % 7;
      const float mu_x = acc[slot][0];
      const float mu_y = acc[slot][1];
      const float mx2 = mu_x * mu_x;
      const float my2 = mu_y * mu_y;
      const float mxy = mu_x * mu_y;
      const float sxx = acc[slot][2] - mx2;
      const float syy = acc[slot][3] - my2;
      const float sxy = acc[slot][4] - mxy;
      const float num = (2.f * mxy + 1e-4f) * (2.f * sxy + 9e-4f);
      const float den = (mx2 + my2 + 1e-4f) * (sxx + syy + 9e-4f);
      tsum += num * __builtin_amdgcn_rcpf(den);
#pragma unroll
      for (int c = 0; c < 5; ++c) acc[slot][c] = 0.f;
    }
  }

  // Block reduction -> one plain store per block.
#pragma unroll
  for (int off = 32; off > 0; off >>= 1) tsum += __shfl_down(tsum, off);
  if ((t & 63) == 0) wsum[t >> 6] = tsum;
  __syncthreads();
  if (t == 0) {
    const int bid = blockIdx.x + 2 * (blockIdx.y + 32 * blockIdx.z);
    partials[bid] = wsum[0] + wsum[1] + wsum[2] + wsum[3];
  }
}

__global__ __launch_bounds__(256) void ssim_reduce(
    const float* __restrict__ partials, float* __restrict__ out) {
  __shared__ double wsum[4];
  const int t = threadIdx.x;
  double s = 0.0;
#pragma unroll
  for (int i = 0; i < NBLK / 256; ++i) s += (double)partials[t + 256 * i];
#pragma unroll
  for (int off = 32; off > 0; off >>= 1) s += __shfl_down(s, off);
  if ((t & 63) == 0) wsum[t >> 6] = s;
  __syncthreads();
  if (t == 0)
    out[0] = (float)((wsum[0] + wsum[1] + wsum[2] + wsum[3]) *
                     (1.0 / (double)((size_t)BATCH * IMG_H * IMG_W)));
}

extern "C" void kernel_launch(void* const* d_in, const int* in_sizes, int n_in,
                              void* d_out, int out_size, void* d_ws, size_t ws_size,
                              hipStream_t stream) {
  const float* X = (const float*)d_in[0];
  const float* Y = (const float*)d_in[1];
  const float* K = (const float*)d_in[2];
  float* out = (float*)d_out;
  float* partials = (float*)d_ws;   // NBLK floats, all rewritten every launch

  dim3 grid(IMG_W / TW, IMG_H / TH, BATCH);  // (2, 32, 32) = 2048 blocks
  hipLaunchKernelGGL(ssim_main, grid, dim3(256), 0, stream, X, Y, K, partials);
  hipLaunchKernelGGL(ssim_reduce, dim3(1), dim3(256), 0, stream, partials, out);
}